// Round 2
// baseline (387.068 us; speedup 1.0000x reference)
//
#include <hip/hip_runtime.h>
#include <hip/hip_bf16.h>
#include <stdint.h>
#include <stddef.h>

// ---------------- workspace layout (bytes) ----------------
// 0     : uint32 flag (0 = f32 inputs, 1 = bf16 inputs)
// 64    : double F[80]        (FF_FILT[t,b] = F[t*8+b], computed in f64)
// 768   : double trace0[16384]
// 131840: double s0[2048]
// 148224: double s1[2048]
#define WS_F_OFF      64
#define WS_TRACE0_OFF 768
#define WS_S0_OFF     131840
#define WS_S1_OFF     148224

// ---------------- threefry2x32 (JAX-exact, 20 rounds) ----------------
__host__ __device__ inline void tf2x32(uint32_t k0, uint32_t k1,
                                       uint32_t& x0, uint32_t& x1) {
  uint32_t ks0 = k0, ks1 = k1, ks2 = k0 ^ k1 ^ 0x1BD11BDAu;
  x0 += ks0; x1 += ks1;
#define TF_ROT(v, n) (((v) << (n)) | ((v) >> (32 - (n))))
#define TF_R(r) { x0 += x1; x1 = TF_ROT(x1, r); x1 ^= x0; }
  TF_R(13) TF_R(15) TF_R(26) TF_R(6)   x0 += ks1; x1 += ks2 + 1u;
  TF_R(17) TF_R(29) TF_R(16) TF_R(24)  x0 += ks2; x1 += ks0 + 2u;
  TF_R(13) TF_R(15) TF_R(26) TF_R(6)   x0 += ks0; x1 += ks1 + 3u;
  TF_R(17) TF_R(29) TF_R(16) TF_R(24)  x0 += ks1; x1 += ks2 + 4u;
  TF_R(13) TF_R(15) TF_R(26) TF_R(6)   x0 += ks2; x1 += ks0 + 5u;
#undef TF_R
#undef TF_ROT
}

__device__ inline double bf2d(unsigned short b) {
  return (double)__uint_as_float(((uint32_t)b) << 16);
}
__device__ inline unsigned short f2bf(float f) {  // RNE
  uint32_t u = __float_as_uint(f);
  u += 0x7FFFu + ((u >> 16) & 1u);
  return (unsigned short)(u >> 16);
}

// ---------------- init: dtype detect + filter table ----------------
__global__ void snn_init_kernel(const uint32_t* __restrict__ x_words,
                                uint8_t* __restrict__ ws) {
  uint32_t* flag = (uint32_t*)ws;
  double* F = (double*)(ws + WS_F_OFF);
  int t = threadIdx.x;
  if (t == 0) {
    int cnt = 0;
    for (int k = 0; k < 256; ++k) {
      uint32_t w = x_words[k];
      cnt += (w == 0u || w == 0x3F800000u) ? 1 : 0;
    }
    *flag = (cnt == 256) ? 0u : 1u;
  }
  if (t < 80) {
    int tt = t >> 3, b = t & 7;
    const double PI = 3.14159265358979311599796346854;
    double arg = 0.5 * PI * log1p((double)tt) - 0.5 * PI * (double)b;
    arg = fmin(fmax(arg, -PI), PI);
    F[t] = 0.5 * (1.0 + cos(arg));
  }
}

// ---------------- trace0[i,b] = sum_t X[i,9-t] * F[t,b] ----------------
__global__ void snn_trace0_kernel(const void* __restrict__ X,
                                  uint8_t* __restrict__ ws) {
  const uint32_t flag = *(const uint32_t*)ws;
  const double* F = (const double*)(ws + WS_F_OFF);
  double* tr = (double*)(ws + WS_TRACE0_OFF);
  int idx = blockIdx.x * blockDim.x + threadIdx.x;
  if (idx >= 2048 * 8) return;
  int i = idx >> 3, b = idx & 7;
  double acc = 0.0;
  if (flag) {
    const unsigned short* Xb = (const unsigned short*)X;
    #pragma unroll
    for (int t = 0; t < 10; ++t) acc += bf2d(Xb[i * 10 + (9 - t)]) * F[t * 8 + b];
  } else {
    const float* Xf = (const float*)X;
    #pragma unroll
    for (int t = 0; t < 10; ++t) acc += (double)Xf[i * 10 + (9 - t)] * F[t * 8 + b];
  }
  tr[idx] = acc;
}

// ---------------- one layer: matvec + sigmoid + bernoulli ----------------
__global__ __launch_bounds__(256) void snn_layer_kernel(
    const void* __restrict__ W, const void* __restrict__ bias,
    uint8_t* __restrict__ ws,
    int traceMode,                 // 0: full trace0, 1: rank-1 via sPrev
    const double* __restrict__ sPrev,
    double* __restrict__ sOutD,    // may be null
    uint32_t key0, uint32_t key1,
    void* __restrict__ out, int pOff, int sOff)
{
  const uint32_t flag = *(const uint32_t*)ws;
  const double* F = (const double*)(ws + WS_F_OFF);
  const double* tr0 = (const double*)(ws + WS_TRACE0_OFF);
  const int o = blockIdx.x;
  const int tid = threadIdx.x;
  double acc = 0.0;

  if (traceMode == 0) {
    if (flag) {
      const unsigned short* Wrow = (const unsigned short*)W + (size_t)o * 16384;
      for (int i = tid; i < 2048; i += 256) {
        uint4 v = *(const uint4*)(Wrow + i * 8);
        const double* tr = tr0 + i * 8;
        acc += bf2d((unsigned short)(v.x & 0xFFFFu)) * tr[0]
             + bf2d((unsigned short)(v.x >> 16))     * tr[1]
             + bf2d((unsigned short)(v.y & 0xFFFFu)) * tr[2]
             + bf2d((unsigned short)(v.y >> 16))     * tr[3]
             + bf2d((unsigned short)(v.z & 0xFFFFu)) * tr[4]
             + bf2d((unsigned short)(v.z >> 16))     * tr[5]
             + bf2d((unsigned short)(v.w & 0xFFFFu)) * tr[6]
             + bf2d((unsigned short)(v.w >> 16))     * tr[7];
      }
    } else {
      const float* Wrow = (const float*)W + (size_t)o * 16384;
      for (int i = tid; i < 2048; i += 256) {
        float4 a = *(const float4*)(Wrow + i * 8);
        float4 b = *(const float4*)(Wrow + i * 8 + 4);
        const double* tr = tr0 + i * 8;
        acc += (double)a.x * tr[0] + (double)a.y * tr[1]
             + (double)a.z * tr[2] + (double)a.w * tr[3]
             + (double)b.x * tr[4] + (double)b.y * tr[5]
             + (double)b.z * tr[6] + (double)b.w * tr[7];
      }
    }
  } else {
    double F0[8];
    #pragma unroll
    for (int b = 0; b < 8; ++b) F0[b] = F[b];
    if (flag) {
      const unsigned short* Wrow = (const unsigned short*)W + (size_t)o * 16384;
      for (int i = tid; i < 2048; i += 256) {
        double si = sPrev[i];
        uint4 v = *(const uint4*)(Wrow + i * 8);
        double dot = bf2d((unsigned short)(v.x & 0xFFFFu)) * F0[0]
                   + bf2d((unsigned short)(v.x >> 16))     * F0[1]
                   + bf2d((unsigned short)(v.y & 0xFFFFu)) * F0[2]
                   + bf2d((unsigned short)(v.y >> 16))     * F0[3]
                   + bf2d((unsigned short)(v.z & 0xFFFFu)) * F0[4]
                   + bf2d((unsigned short)(v.z >> 16))     * F0[5]
                   + bf2d((unsigned short)(v.w & 0xFFFFu)) * F0[6]
                   + bf2d((unsigned short)(v.w >> 16))     * F0[7];
        acc += si * dot;
      }
    } else {
      const float* Wrow = (const float*)W + (size_t)o * 16384;
      for (int i = tid; i < 2048; i += 256) {
        double si = sPrev[i];
        float4 a = *(const float4*)(Wrow + i * 8);
        float4 b = *(const float4*)(Wrow + i * 8 + 4);
        double dot = (double)a.x * F0[0] + (double)a.y * F0[1]
                   + (double)a.z * F0[2] + (double)a.w * F0[3]
                   + (double)b.x * F0[4] + (double)b.y * F0[5]
                   + (double)b.z * F0[6] + (double)b.w * F0[7];
        acc += si * dot;
      }
    }
  }

  __shared__ double red[256];
  red[tid] = acc;
  __syncthreads();
  for (int s = 128; s > 0; s >>= 1) {
    if (tid < s) red[tid] += red[tid + s];
    __syncthreads();
  }

  if (tid == 0) {
    double bb = flag ? bf2d(((const unsigned short*)bias)[o])
                     : (double)((const float*)bias)[o];
    double x = red[0] + bb;
    double p = 1.0 / (1.0 + exp(-x));
    // JAX partitionable (counter-mode) uniform: element o -> block x=(0,o),
    // 32-bit value = out0 ^ out1.
    uint32_t x0 = 0u, x1 = (uint32_t)o;
    tf2x32(key0, key1, x0, x1);
    uint32_t wbits = x0 ^ x1;
    float u = __uint_as_float((wbits >> 9) | 0x3F800000u) - 1.0f;
    double s = ((double)u < p) ? 1.0 : 0.0;
    if (flag) {
      unsigned short* ob = (unsigned short*)out;
      ob[pOff + o] = f2bf((float)p);
      ob[sOff + o] = f2bf((float)s);
    } else {
      float* of = (float*)out;
      of[pOff + o] = (float)p;
      of[sOff + o] = (float)s;
    }
    if (sOutD) sOutD[o] = s;
  }
}

extern "C" void kernel_launch(void* const* d_in, const int* in_sizes, int n_in,
                              void* d_out, int out_size, void* d_ws, size_t ws_size,
                              hipStream_t stream) {
  // keys: split(key(42), 3), partitionable/fold-like scheme:
  // k_i = threefry2x32((0,42), x=(0,i)), new key = (out0, out1).
  uint32_t k0a = 0u, k0b = 0u;  tf2x32(0u, 42u, k0a, k0b);
  uint32_t k1a = 0u, k1b = 1u;  tf2x32(0u, 42u, k1a, k1b);
  uint32_t k2a = 0u, k2b = 2u;  tf2x32(0u, 42u, k2a, k2b);

  uint8_t* ws = (uint8_t*)d_ws;
  double* s0d = (double*)(ws + WS_S0_OFF);
  double* s1d = (double*)(ws + WS_S1_OFF);

  snn_init_kernel<<<1, 128, 0, stream>>>((const uint32_t*)d_in[0], ws);
  snn_trace0_kernel<<<64, 256, 0, stream>>>(d_in[0], ws);
  // layer 0: W0=d_in[1], b0=d_in[3]; p0 -> out[4096..], s0 -> out[8192..]
  snn_layer_kernel<<<2048, 256, 0, stream>>>(d_in[1], d_in[3], ws, 0, nullptr, s0d,
                                             k0a, k0b, d_out, 4096, 8192);
  // layer 1: W1=d_in[4], b1=d_in[6]; p1 -> out[6144..], s1 -> out[10240..]
  snn_layer_kernel<<<2048, 256, 0, stream>>>(d_in[4], d_in[6], ws, 1, s0d, s1d,
                                             k1a, k1b, d_out, 6144, 10240);
  // layer 2: W2=d_in[7], b2=d_in[9]; p2 -> out[0..], s2 -> out[2048..]
  snn_layer_kernel<<<2048, 256, 0, stream>>>(d_in[7], d_in[9], ws, 1, s1d, nullptr,
                                             k2a, k2b, d_out, 0, 2048);
}

// Round 3
// 376.546 us; speedup vs baseline: 1.0279x; 1.0279x over previous
//
#include <hip/hip_runtime.h>
#include <hip/hip_bf16.h>
#include <stdint.h>
#include <stddef.h>

// ---------------- workspace layout (bytes) ----------------
// 0     : uint32 flag (0 = f32 inputs, 1 = bf16 inputs)
// 64    : double F[80]        (FF_FILT[t,b] = F[t*8+b], f64)
// 768   : double trace0[16384]
// 131840: double s0[2048]
// 148224: double s1[2048]
#define WS_F_OFF      64
#define WS_TRACE0_OFF 768
#define WS_S0_OFF     131840
#define WS_S1_OFF     148224

// ---------------- threefry2x32 (JAX-exact, 20 rounds) ----------------
__host__ __device__ inline void tf2x32(uint32_t k0, uint32_t k1,
                                       uint32_t& x0, uint32_t& x1) {
  uint32_t ks0 = k0, ks1 = k1, ks2 = k0 ^ k1 ^ 0x1BD11BDAu;
  x0 += ks0; x1 += ks1;
#define TF_ROT(v, n) (((v) << (n)) | ((v) >> (32 - (n))))
#define TF_R(r) { x0 += x1; x1 = TF_ROT(x1, r); x1 ^= x0; }
  TF_R(13) TF_R(15) TF_R(26) TF_R(6)   x0 += ks1; x1 += ks2 + 1u;
  TF_R(17) TF_R(29) TF_R(16) TF_R(24)  x0 += ks2; x1 += ks0 + 2u;
  TF_R(13) TF_R(15) TF_R(26) TF_R(6)   x0 += ks0; x1 += ks1 + 3u;
  TF_R(17) TF_R(29) TF_R(16) TF_R(24)  x0 += ks1; x1 += ks2 + 4u;
  TF_R(13) TF_R(15) TF_R(26) TF_R(6)   x0 += ks2; x1 += ks0 + 5u;
#undef TF_R
#undef TF_ROT
}

__device__ inline double bf2d(unsigned short b) {
  return (double)__uint_as_float(((uint32_t)b) << 16);
}
__device__ inline unsigned short f2bf(float f) {  // RNE
  uint32_t u = __float_as_uint(f);
  u += 0x7FFFu + ((u >> 16) & 1u);
  return (unsigned short)(u >> 16);
}

// ---- prep: dtype flag (parallel ballot) + F table + trace0 ----
// grid 64 x 256; work item idx = (i,b), idx = i*8+b
__global__ __launch_bounds__(256) void snn_prep_kernel(
    const void* __restrict__ X, uint8_t* __restrict__ ws) {
  __shared__ unsigned long long smask[4];
  __shared__ double sF[80];
  __shared__ int s_flag;
  const int tid = threadIdx.x;

  // dtype detect: 256 threads, 1 word each, ballot-reduce (no serial loop)
  const uint32_t* xw = (const uint32_t*)X;
  uint32_t w = xw[tid];
  bool ok = (w == 0u || w == 0x3F800000u);
  unsigned long long m = __ballot(ok);
  if ((tid & 63) == 0) smask[tid >> 6] = m;

  // F table: 80 threads compute f64 raised-cosine entries
  if (tid < 80) {
    int tt = tid >> 3, b = tid & 7;
    const double PI = 3.14159265358979311599796346854;
    double arg = 0.5 * PI * log1p((double)tt) - 0.5 * PI * (double)b;
    arg = fmin(fmax(arg, -PI), PI);
    sF[tid] = 0.5 * (1.0 + cos(arg));
  }
  __syncthreads();
  if (tid == 0) {
    bool allbin = ((smask[0] & smask[1] & smask[2] & smask[3]) == ~0ull);
    s_flag = allbin ? 0 : 1;   // all exact {0.0f,1.0f} words -> f32 input
  }
  __syncthreads();
  const int flag = s_flag;

  if (blockIdx.x == 0) {
    if (tid == 0) *(uint32_t*)ws = (uint32_t)flag;
    if (tid < 80) ((double*)(ws + WS_F_OFF))[tid] = sF[tid];
  }

  const int idx = blockIdx.x * 256 + tid;   // 0..16383
  const int i = idx >> 3, b = idx & 7;
  double acc = 0.0;
  if (flag) {
    const unsigned short* Xb = (const unsigned short*)X;
    #pragma unroll
    for (int t = 0; t < 10; ++t) acc += bf2d(Xb[i * 10 + (9 - t)]) * sF[t * 8 + b];
  } else {
    const float* Xf = (const float*)X;
    #pragma unroll
    for (int t = 0; t < 10; ++t) acc += (double)Xf[i * 10 + (9 - t)] * sF[t * 8 + b];
  }
  ((double*)(ws + WS_TRACE0_OFF))[idx] = acc;
}

// ---- layer: wave-per-row matvec, shfl reduce, sigmoid + bernoulli ----
// grid 512 x 256 (4 waves/block, 1 row per wave)
__global__ __launch_bounds__(256) void snn_layer_kernel(
    const void* __restrict__ W, const void* __restrict__ bias,
    const uint8_t* __restrict__ ws,
    int traceMode,                 // 0: full trace0, 1: rank-1 via sPrev
    const double* __restrict__ sPrev,
    double* __restrict__ sOutD,    // may be null
    uint32_t key0, uint32_t key1,
    void* __restrict__ out, int pOff, int sOff)
{
  const uint32_t flag = *(const uint32_t*)ws;
  const double* F = (const double*)(ws + WS_F_OFF);
  const double* tr0 = (const double*)(ws + WS_TRACE0_OFF);
  const int lane = threadIdx.x & 63;
  const int row = blockIdx.x * 4 + (threadIdx.x >> 6);

  double acc[8];
  #pragma unroll
  for (int b = 0; b < 8; ++b) acc[b] = 0.0;

  if (traceMode == 0) {
    if (flag) {
      const unsigned short* Wr = (const unsigned short*)W + (size_t)row * 16384;
      for (int s = 0; s < 32; ++s) {
        int i = s * 64 + lane;
        uint4 v = *(const uint4*)(Wr + i * 8);
        const double2* t = (const double2*)(tr0 + i * 8);
        double2 t0 = t[0], t1 = t[1], t2 = t[2], t3 = t[3];
        acc[0] += bf2d((unsigned short)(v.x & 0xFFFFu)) * t0.x;
        acc[1] += bf2d((unsigned short)(v.x >> 16))     * t0.y;
        acc[2] += bf2d((unsigned short)(v.y & 0xFFFFu)) * t1.x;
        acc[3] += bf2d((unsigned short)(v.y >> 16))     * t1.y;
        acc[4] += bf2d((unsigned short)(v.z & 0xFFFFu)) * t2.x;
        acc[5] += bf2d((unsigned short)(v.z >> 16))     * t2.y;
        acc[6] += bf2d((unsigned short)(v.w & 0xFFFFu)) * t3.x;
        acc[7] += bf2d((unsigned short)(v.w >> 16))     * t3.y;
      }
    } else {
      const float* Wr = (const float*)W + (size_t)row * 16384;
      for (int s = 0; s < 32; ++s) {
        int i = s * 64 + lane;
        float4 a = *(const float4*)(Wr + i * 8);
        float4 c = *(const float4*)(Wr + i * 8 + 4);
        const double2* t = (const double2*)(tr0 + i * 8);
        double2 t0 = t[0], t1 = t[1], t2 = t[2], t3 = t[3];
        acc[0] += (double)a.x * t0.x;  acc[1] += (double)a.y * t0.y;
        acc[2] += (double)a.z * t1.x;  acc[3] += (double)a.w * t1.y;
        acc[4] += (double)c.x * t2.x;  acc[5] += (double)c.y * t2.y;
        acc[6] += (double)c.z * t3.x;  acc[7] += (double)c.w * t3.y;
      }
    }
  } else {
    double F0[8];
    #pragma unroll
    for (int b = 0; b < 8; ++b) F0[b] = F[b];
    if (flag) {
      const unsigned short* Wr = (const unsigned short*)W + (size_t)row * 16384;
      for (int s = 0; s < 32; ++s) {
        int i = s * 64 + lane;
        uint4 v = *(const uint4*)(Wr + i * 8);
        double si = sPrev[i];
        acc[0] += (bf2d((unsigned short)(v.x & 0xFFFFu)) * F0[0]) * si;
        acc[1] += (bf2d((unsigned short)(v.x >> 16))     * F0[1]) * si;
        acc[2] += (bf2d((unsigned short)(v.y & 0xFFFFu)) * F0[2]) * si;
        acc[3] += (bf2d((unsigned short)(v.y >> 16))     * F0[3]) * si;
        acc[4] += (bf2d((unsigned short)(v.z & 0xFFFFu)) * F0[4]) * si;
        acc[5] += (bf2d((unsigned short)(v.z >> 16))     * F0[5]) * si;
        acc[6] += (bf2d((unsigned short)(v.w & 0xFFFFu)) * F0[6]) * si;
        acc[7] += (bf2d((unsigned short)(v.w >> 16))     * F0[7]) * si;
      }
    } else {
      const float* Wr = (const float*)W + (size_t)row * 16384;
      for (int s = 0; s < 32; ++s) {
        int i = s * 64 + lane;
        float4 a = *(const float4*)(Wr + i * 8);
        float4 c = *(const float4*)(Wr + i * 8 + 4);
        double si = sPrev[i];
        acc[0] += ((double)a.x * F0[0]) * si;
        acc[1] += ((double)a.y * F0[1]) * si;
        acc[2] += ((double)a.z * F0[2]) * si;
        acc[3] += ((double)a.w * F0[3]) * si;
        acc[4] += ((double)c.x * F0[4]) * si;
        acc[5] += ((double)c.y * F0[5]) * si;
        acc[6] += ((double)c.z * F0[6]) * si;
        acc[7] += ((double)c.w * F0[7]) * si;
      }
    }
  }

  double r = ((acc[0] + acc[1]) + (acc[2] + acc[3])) +
             ((acc[4] + acc[5]) + (acc[6] + acc[7]));
  #pragma unroll
  for (int off = 32; off > 0; off >>= 1) r += __shfl_down(r, off, 64);

  if (lane == 0) {
    double bb = flag ? bf2d(((const unsigned short*)bias)[row])
                     : (double)((const float*)bias)[row];
    double x = r + bb;
    double p = 1.0 / (1.0 + exp(-x));
    // JAX partitionable counter-mode uniform: element o -> block x=(0,o),
    // bits = out0 ^ out1
    uint32_t x0 = 0u, x1 = (uint32_t)row;
    tf2x32(key0, key1, x0, x1);
    uint32_t wbits = x0 ^ x1;
    float u = __uint_as_float((wbits >> 9) | 0x3F800000u) - 1.0f;
    double sp = ((double)u < p) ? 1.0 : 0.0;
    if (flag) {
      unsigned short* ob = (unsigned short*)out;
      ob[pOff + row] = f2bf((float)p);
      ob[sOff + row] = f2bf((float)sp);
    } else {
      float* of = (float*)out;
      of[pOff + row] = (float)p;
      of[sOff + row] = (float)sp;
    }
    if (sOutD) sOutD[row] = sp;
  }
}

extern "C" void kernel_launch(void* const* d_in, const int* in_sizes, int n_in,
                              void* d_out, int out_size, void* d_ws, size_t ws_size,
                              hipStream_t stream) {
  // keys: split(key(42), 3), partitionable scheme:
  // k_i = threefry2x32((0,42), x=(0,i)), new key = (out0, out1).
  uint32_t k0a = 0u, k0b = 0u;  tf2x32(0u, 42u, k0a, k0b);
  uint32_t k1a = 0u, k1b = 1u;  tf2x32(0u, 42u, k1a, k1b);
  uint32_t k2a = 0u, k2b = 2u;  tf2x32(0u, 42u, k2a, k2b);

  uint8_t* ws = (uint8_t*)d_ws;
  double* s0d = (double*)(ws + WS_S0_OFF);
  double* s1d = (double*)(ws + WS_S1_OFF);

  snn_prep_kernel<<<64, 256, 0, stream>>>(d_in[0], ws);
  // layer 0: W0=d_in[1], b0=d_in[3]; p0 -> out[4096..], s0 -> out[8192..]
  snn_layer_kernel<<<512, 256, 0, stream>>>(d_in[1], d_in[3], ws, 0, nullptr, s0d,
                                            k0a, k0b, d_out, 4096, 8192);
  // layer 1: W1=d_in[4], b1=d_in[6]; p1 -> out[6144..], s1 -> out[10240..]
  snn_layer_kernel<<<512, 256, 0, stream>>>(d_in[4], d_in[6], ws, 1, s0d, s1d,
                                            k1a, k1b, d_out, 6144, 10240);
  // layer 2: W2=d_in[7], b2=d_in[9]; p2 -> out[0..], s2 -> out[2048..]
  snn_layer_kernel<<<512, 256, 0, stream>>>(d_in[7], d_in[9], ws, 1, s1d, nullptr,
                                            k2a, k2b, d_out, 0, 2048);
}

// Round 4
// 373.377 us; speedup vs baseline: 1.0367x; 1.0085x over previous
//
#include <hip/hip_runtime.h>
#include <hip/hip_bf16.h>
#include <stdint.h>
#include <stddef.h>

// ---------------- workspace layout (bytes) ----------------
// 0     : uint32 flag (0 = f32 inputs, 1 = bf16 inputs)
// 64    : double F[80]          (FF_FILT[t,b] = F[t*8+b], f64)
// 768   : double trT[8][2048]   (transposed trace0, coalesced reads)
// 131840: double s0[2048]
// 148224: double s1[2048]
#define WS_F_OFF      64
#define WS_TRACE0_OFF 768
#define WS_S0_OFF     131840
#define WS_S1_OFF     148224

// ---------------- threefry2x32 (JAX-exact, 20 rounds) ----------------
__host__ __device__ inline void tf2x32(uint32_t k0, uint32_t k1,
                                       uint32_t& x0, uint32_t& x1) {
  uint32_t ks0 = k0, ks1 = k1, ks2 = k0 ^ k1 ^ 0x1BD11BDAu;
  x0 += ks0; x1 += ks1;
#define TF_ROT(v, n) (((v) << (n)) | ((v) >> (32 - (n))))
#define TF_R(r) { x0 += x1; x1 = TF_ROT(x1, r); x1 ^= x0; }
  TF_R(13) TF_R(15) TF_R(26) TF_R(6)   x0 += ks1; x1 += ks2 + 1u;
  TF_R(17) TF_R(29) TF_R(16) TF_R(24)  x0 += ks2; x1 += ks0 + 2u;
  TF_R(13) TF_R(15) TF_R(26) TF_R(6)   x0 += ks0; x1 += ks1 + 3u;
  TF_R(17) TF_R(29) TF_R(16) TF_R(24)  x0 += ks1; x1 += ks2 + 4u;
  TF_R(13) TF_R(15) TF_R(26) TF_R(6)   x0 += ks2; x1 += ks0 + 5u;
#undef TF_R
#undef TF_ROT
}

__device__ inline double bf2d(unsigned short b) {
  return (double)__uint_as_float(((uint32_t)b) << 16);
}
__device__ inline unsigned short f2bf(float f) {  // RNE
  uint32_t u = __float_as_uint(f);
  u += 0x7FFFu + ((u >> 16) & 1u);
  return (unsigned short)(u >> 16);
}

// ---- prep: dtype flag (ballot) + F table + transposed trace0 ----
// grid 64 x 256; item idx = i*8+b; stores trT[b*2048+i]
__global__ __launch_bounds__(256) void snn_prep_kernel(
    const void* __restrict__ X, uint8_t* __restrict__ ws) {
  __shared__ unsigned long long smask[4];
  __shared__ double sF[80];
  __shared__ int s_flag;
  const int tid = threadIdx.x;

  const uint32_t* xw = (const uint32_t*)X;
  uint32_t w = xw[tid];
  bool ok = (w == 0u || w == 0x3F800000u);
  unsigned long long m = __ballot(ok);
  if ((tid & 63) == 0) smask[tid >> 6] = m;

  if (tid < 80) {
    int tt = tid >> 3, b = tid & 7;
    const double PI = 3.14159265358979311599796346854;
    double arg = 0.5 * PI * log1p((double)tt) - 0.5 * PI * (double)b;
    arg = fmin(fmax(arg, -PI), PI);
    sF[tid] = 0.5 * (1.0 + cos(arg));
  }
  __syncthreads();
  if (tid == 0) {
    bool allbin = ((smask[0] & smask[1] & smask[2] & smask[3]) == ~0ull);
    s_flag = allbin ? 0 : 1;   // all exact {0.0f,1.0f} words -> f32 input
  }
  __syncthreads();
  const int flag = s_flag;

  if (blockIdx.x == 0) {
    if (tid == 0) *(uint32_t*)ws = (uint32_t)flag;
    if (tid < 80) ((double*)(ws + WS_F_OFF))[tid] = sF[tid];
  }

  const int idx = blockIdx.x * 256 + tid;   // 0..16383
  const int i = idx >> 3, b = idx & 7;
  double acc = 0.0;
  if (flag) {
    const unsigned short* Xb = (const unsigned short*)X;
    #pragma unroll
    for (int t = 0; t < 10; ++t) acc += bf2d(Xb[i * 10 + (9 - t)]) * sF[t * 8 + b];
  } else {
    const float* Xf = (const float*)X;
    #pragma unroll
    for (int t = 0; t < 10; ++t) acc += (double)Xf[i * 10 + (9 - t)] * sF[t * 8 + b];
  }
  ((double*)(ws + WS_TRACE0_OFF))[b * 2048 + i] = acc;   // transposed store
}

// ---- layer: 2 waves per row, shfl + tiny-LDS reduce, sigmoid + RNG ----
// grid 1024 x 256 (4 waves/block = 2 rows/block, each row split in half)
__global__ __launch_bounds__(256) void snn_layer_kernel(
    const void* __restrict__ W, const void* __restrict__ bias,
    const uint8_t* __restrict__ ws,
    int traceMode,                 // 0: full trace0 (transposed), 1: rank-1
    const double* __restrict__ sPrev,
    double* __restrict__ sOutD,    // may be null
    uint32_t key0, uint32_t key1,
    void* __restrict__ out, int pOff, int sOff)
{
  const uint32_t flag = *(const uint32_t*)ws;
  const double* F = (const double*)(ws + WS_F_OFF);
  const double* trT = (const double*)(ws + WS_TRACE0_OFF);
  const int lane = threadIdx.x & 63;
  const int wid  = threadIdx.x >> 6;          // 0..3
  const int row  = blockIdx.x * 2 + (wid >> 1);
  const int half = wid & 1;                   // which 1024-wide half of i
  const int ibase = half * 1024;

  double acc[8];
  #pragma unroll
  for (int b = 0; b < 8; ++b) acc[b] = 0.0;

  if (traceMode == 0) {
    if (flag) {
      const unsigned short* Wr = (const unsigned short*)W + (size_t)row * 16384;
      #pragma unroll 4
      for (int s = 0; s < 16; ++s) {
        int i = ibase + s * 64 + lane;
        uint4 v = *(const uint4*)(Wr + i * 8);
        acc[0] += bf2d((unsigned short)(v.x & 0xFFFFu)) * trT[0 * 2048 + i];
        acc[1] += bf2d((unsigned short)(v.x >> 16))     * trT[1 * 2048 + i];
        acc[2] += bf2d((unsigned short)(v.y & 0xFFFFu)) * trT[2 * 2048 + i];
        acc[3] += bf2d((unsigned short)(v.y >> 16))     * trT[3 * 2048 + i];
        acc[4] += bf2d((unsigned short)(v.z & 0xFFFFu)) * trT[4 * 2048 + i];
        acc[5] += bf2d((unsigned short)(v.z >> 16))     * trT[5 * 2048 + i];
        acc[6] += bf2d((unsigned short)(v.w & 0xFFFFu)) * trT[6 * 2048 + i];
        acc[7] += bf2d((unsigned short)(v.w >> 16))     * trT[7 * 2048 + i];
      }
    } else {
      const float* Wr = (const float*)W + (size_t)row * 16384;
      #pragma unroll 4
      for (int s = 0; s < 16; ++s) {
        int i = ibase + s * 64 + lane;
        float4 a = *(const float4*)(Wr + i * 8);
        float4 c = *(const float4*)(Wr + i * 8 + 4);
        acc[0] += (double)a.x * trT[0 * 2048 + i];
        acc[1] += (double)a.y * trT[1 * 2048 + i];
        acc[2] += (double)a.z * trT[2 * 2048 + i];
        acc[3] += (double)a.w * trT[3 * 2048 + i];
        acc[4] += (double)c.x * trT[4 * 2048 + i];
        acc[5] += (double)c.y * trT[5 * 2048 + i];
        acc[6] += (double)c.z * trT[6 * 2048 + i];
        acc[7] += (double)c.w * trT[7 * 2048 + i];
      }
    }
  } else {
    double F0[8];
    #pragma unroll
    for (int b = 0; b < 8; ++b) F0[b] = F[b];
    if (flag) {
      const unsigned short* Wr = (const unsigned short*)W + (size_t)row * 16384;
      #pragma unroll 4
      for (int s = 0; s < 16; ++s) {
        int i = ibase + s * 64 + lane;
        uint4 v = *(const uint4*)(Wr + i * 8);
        double si = sPrev[i];
        acc[0] += (bf2d((unsigned short)(v.x & 0xFFFFu)) * F0[0]) * si;
        acc[1] += (bf2d((unsigned short)(v.x >> 16))     * F0[1]) * si;
        acc[2] += (bf2d((unsigned short)(v.y & 0xFFFFu)) * F0[2]) * si;
        acc[3] += (bf2d((unsigned short)(v.y >> 16))     * F0[3]) * si;
        acc[4] += (bf2d((unsigned short)(v.z & 0xFFFFu)) * F0[4]) * si;
        acc[5] += (bf2d((unsigned short)(v.z >> 16))     * F0[5]) * si;
        acc[6] += (bf2d((unsigned short)(v.w & 0xFFFFu)) * F0[6]) * si;
        acc[7] += (bf2d((unsigned short)(v.w >> 16))     * F0[7]) * si;
      }
    } else {
      const float* Wr = (const float*)W + (size_t)row * 16384;
      #pragma unroll 4
      for (int s = 0; s < 16; ++s) {
        int i = ibase + s * 64 + lane;
        float4 a = *(const float4*)(Wr + i * 8);
        float4 c = *(const float4*)(Wr + i * 8 + 4);
        double si = sPrev[i];
        acc[0] += ((double)a.x * F0[0]) * si;
        acc[1] += ((double)a.y * F0[1]) * si;
        acc[2] += ((double)a.z * F0[2]) * si;
        acc[3] += ((double)a.w * F0[3]) * si;
        acc[4] += ((double)c.x * F0[4]) * si;
        acc[5] += ((double)c.y * F0[5]) * si;
        acc[6] += ((double)c.z * F0[6]) * si;
        acc[7] += ((double)c.w * F0[7]) * si;
      }
    }
  }

  double r = ((acc[0] + acc[1]) + (acc[2] + acc[3])) +
             ((acc[4] + acc[5]) + (acc[6] + acc[7]));
  #pragma unroll
  for (int off = 32; off > 0; off >>= 1) r += __shfl_down(r, off, 64);

  __shared__ double sred[4];
  if (lane == 0) sred[wid] = r;
  __syncthreads();

  if (threadIdx.x < 2) {
    const int o = blockIdx.x * 2 + threadIdx.x;        // this thread's row
    double rr = sred[2 * threadIdx.x] + sred[2 * threadIdx.x + 1];
    double bb = flag ? bf2d(((const unsigned short*)bias)[o])
                     : (double)((const float*)bias)[o];
    double x = rr + bb;
    double p = 1.0 / (1.0 + exp(-x));
    // JAX partitionable counter-mode uniform: element o -> block x=(0,o),
    // bits = out0 ^ out1
    uint32_t x0 = 0u, x1 = (uint32_t)o;
    tf2x32(key0, key1, x0, x1);
    uint32_t wbits = x0 ^ x1;
    float u = __uint_as_float((wbits >> 9) | 0x3F800000u) - 1.0f;
    double sp = ((double)u < p) ? 1.0 : 0.0;
    if (flag) {
      unsigned short* ob = (unsigned short*)out;
      ob[pOff + o] = f2bf((float)p);
      ob[sOff + o] = f2bf((float)sp);
    } else {
      float* of = (float*)out;
      of[pOff + o] = (float)p;
      of[sOff + o] = (float)sp;
    }
    if (sOutD) sOutD[o] = sp;
  }
}

extern "C" void kernel_launch(void* const* d_in, const int* in_sizes, int n_in,
                              void* d_out, int out_size, void* d_ws, size_t ws_size,
                              hipStream_t stream) {
  // keys: split(key(42), 3), partitionable scheme:
  // k_i = threefry2x32((0,42), x=(0,i)), new key = (out0, out1).
  uint32_t k0a = 0u, k0b = 0u;  tf2x32(0u, 42u, k0a, k0b);
  uint32_t k1a = 0u, k1b = 1u;  tf2x32(0u, 42u, k1a, k1b);
  uint32_t k2a = 0u, k2b = 2u;  tf2x32(0u, 42u, k2a, k2b);

  uint8_t* ws = (uint8_t*)d_ws;
  double* s0d = (double*)(ws + WS_S0_OFF);
  double* s1d = (double*)(ws + WS_S1_OFF);

  snn_prep_kernel<<<64, 256, 0, stream>>>(d_in[0], ws);
  // layer 0: W0=d_in[1], b0=d_in[3]; p0 -> out[4096..], s0 -> out[8192..]
  snn_layer_kernel<<<1024, 256, 0, stream>>>(d_in[1], d_in[3], ws, 0, nullptr, s0d,
                                             k0a, k0b, d_out, 4096, 8192);
  // layer 1: W1=d_in[4], b1=d_in[6]; p1 -> out[6144..], s1 -> out[10240..]
  snn_layer_kernel<<<1024, 256, 0, stream>>>(d_in[4], d_in[6], ws, 1, s0d, s1d,
                                             k1a, k1b, d_out, 6144, 10240);
  // layer 2: W2=d_in[7], b2=d_in[9]; p2 -> out[0..], s2 -> out[2048..]
  snn_layer_kernel<<<1024, 256, 0, stream>>>(d_in[7], d_in[9], ws, 1, s1d, nullptr,
                                             k2a, k2b, d_out, 0, 2048);
}